// Round 18
// baseline (172.576 us; speedup 1.0000x reference)
//
#include <hip/hip_runtime.h>
#include <hip/hip_fp16.h>
#include <cstdint>

#define N_NODES 4096
#define IN_FEAT 256
#define OUT_FEAT 64
#define NHEAD 8
#define LOG2E 1.4426950408889634f

typedef _Float16 f16;
typedef f16   f16x2 __attribute__((ext_vector_type(2)));
typedef f16   f16x8 __attribute__((ext_vector_type(8)));
typedef float f32x4 __attribute__((ext_vector_type(4)));

// ws layout (bytes) — total 30,015,488 (< 38.8 MB proven in r3):
//   h_t   @ 0        : 8*64*4096*2 = 4194304   f16 [h][feat][node]
//   srcPK @ 4194304  : 8*4096*4    = 131072    dword {E1s,E5s} f16 pair per (h,n)
//   dstE1 @ 4325376  : 8*4096*2    = 65536     f16 exp2(t_d) per (h,m)
//   dstE5 @ 4390912  : 8*4096*2    = 65536     f16 exp2(0.2 t_d)
//   emask @ 4718592  : 4096*4096   = 16777216  byte 0xFF/0x00 = adj!=0
//   numA  @ 21495808 : 4096*8*64*4 = 8388608   f32 atomic accumulators
//   denA  @ 29884416 : 4096*8*4    = 131072
#define OFF_SRCPK 4194304
#define OFF_DSTE1 4325376
#define OFF_DSTE5 4390912
#define OFF_EM    4718592
#define OFF_NUMA  21495808ULL
#define OFF_DENA  29884416ULL

union HU { unsigned u; f16x2 h; };
union A8 { f16x8 v; unsigned u[4]; };

__device__ __forceinline__ void async_copy16(const void* g, void* l) {
    __builtin_amdgcn_global_load_lds(
        (const __attribute__((address_space(1))) void*)g,
        (__attribute__((address_space(3))) void*)l, 16, 0, 0);
}

static __device__ inline unsigned pkh2(float a, float b) {
    union { f16 h[2]; unsigned u; } t;
    t.h[0] = (f16)a; t.h[1] = (f16)b; return t.u;
}

// ---------------------------------------------------------------------------
// r18 fused front end (one dispatch). Branches by blockIdx:
//   [0,512)      phase1: h = x@W[h] (f16 MFMA). r18 FIX: W slab staged into
//                LDS per k0 (coalesced float4 -> ds_write_b128, wave-private,
//                no barrier) — replaces r17's 1024 strided scalar L2 loads
//                per wave (the r2 pathology that made prep ~50us).
//   [512,1536)   adj -> emask bytes (elementwise, coalesced)
//   [1536,2576)  zero numA/denA
// LDS 25.3 KB/block -> 4 blocks/CU for all branches.
// ---------------------------------------------------------------------------
__global__ __launch_bounds__(256, 4) void gat_prep(
    const int*   __restrict__ adj,
    unsigned*    __restrict__ em32,
    float*       __restrict__ zeroBase,
    const float* __restrict__ x,      // [4096][256]
    const float* __restrict__ W,      // [8][256][64]
    const float* __restrict__ a,      // [8][128]
    f16*      __restrict__ h_t,
    unsigned* __restrict__ srcPK,
    f16*      __restrict__ dstE1,
    f16*      __restrict__ dstE5)
{
    __shared__ f16 xs[16][264];        // 8448 B
    __shared__ f16 wsw[4][32][66];     // 16896 B, pad 66: u16 frag reads
                                       // bank = (k + 8f + (r>>1)) % 32 — all
                                       // 32 banks covered, conflict-free

    if (blockIdx.x >= 1536) {   // zero branch: 1040 blocks x 2048 floats
        size_t off = ((size_t)(blockIdx.x - 1536) * 256 + threadIdx.x) * 8;
        float4 z = {0.f, 0.f, 0.f, 0.f};
        *(float4*)(zeroBase + off)     = z;
        *(float4*)(zeroBase + off + 4) = z;
        return;
    }
    if (blockIdx.x >= 512) {    // emask branch: wave per row
        const int bi   = blockIdx.x - 512;
        const int wv   = threadIdx.x >> 6;
        const int lane = threadIdx.x & 63;
        const int row  = bi * 4 + wv;
        const int* p   = adj + (size_t)row * N_NODES;
        unsigned* dst  = em32 + (size_t)row * (N_NODES / 4);
        #pragma unroll 4
        for (int s = 0; s < 16; ++s) {
            int4 v = *(const int4*)(p + s * 256 + lane * 4);
            unsigned d = (v.x ? 0x000000FFu : 0u) | (v.y ? 0x0000FF00u : 0u)
                       | (v.z ? 0x00FF0000u : 0u) | (v.w ? 0xFF000000u : 0u);
            dst[s * 64 + lane] = d;
        }
        return;
    }

    // ---- phase1 branch (blocks 0..511) ----
    const int lane = threadIdx.x & 63;
    const int wv   = threadIdx.x >> 6;
    const int tile = blockIdx.x >> 1;
    const int hd   = (blockIdx.x & 1) * 4 + wv;
    const int r    = lane & 15;
    const int q    = lane >> 4;
    const int nb   = tile * 16;

    #pragma unroll
    for (int c = 0; c < 4; ++c) {
        int idx = c * 1024 + threadIdx.x * 4;
        int row = idx >> 8, col = idx & 255;
        float4 v = *(const float4*)(x + (size_t)(nb + row) * IN_FEAT + col);
        uint2 st = { pkh2(v.x, v.y), pkh2(v.z, v.w) };
        *(uint2*)(&xs[row][col]) = st;
    }
    __syncthreads();

    const float* Wg   = W + (size_t)hd * (IN_FEAT * OUT_FEAT);
    const int    krow = lane >> 1;          // 0..31: slab row this lane stages
    const int    half = (lane & 1) * 32;    // col half
    f32x4 acc[4] = {};

    #pragma unroll 2
    for (int k0 = 0; k0 < IN_FEAT; k0 += 32) {
        // stage W slab [k0..k0+32) x 64 cols -> wsw[wv] (coalesced float4,
        // packed f16, b128 LDS writes; wave-private so no __syncthreads —
        // DS ops are wave-ordered)
        const float* wsrc = Wg + (size_t)(k0 + krow) * OUT_FEAT + half;
        #pragma unroll
        for (int i = 0; i < 4; ++i) {
            float4 va = *(const float4*)(wsrc + i * 8);
            float4 vb = *(const float4*)(wsrc + i * 8 + 4);
            uint4 st = { pkh2(va.x, va.y), pkh2(va.z, va.w),
                         pkh2(vb.x, vb.y), pkh2(vb.z, vb.w) };
            *(uint4*)(&wsw[wv][krow][half + i * 8]) = st;
        }

        f16x8 af = *(const f16x8*)(&xs[r][k0 + q * 8]);
        #pragma unroll
        for (int f = 0; f < 4; ++f) {
            f16x8 bf;   // B[k=q*8+j][col=16f+r] from LDS slab
            #pragma unroll
            for (int j = 0; j < 8; ++j)
                bf[j] = wsw[wv][q * 8 + j][16 * f + r];
            acc[f] = __builtin_amdgcn_mfma_f32_16x16x32_f16(af, bf, acc[f], 0, 0, 0);
        }
    }

    float asv[4], adv[4];
    #pragma unroll
    for (int f = 0; f < 4; ++f) {
        asv[f] = a[hd * 128 + 16 * f + r];
        adv[f] = a[hd * 128 + 64 + 16 * f + r];
    }
    float sp[4], dp[4];
    #pragma unroll
    for (int reg = 0; reg < 4; ++reg) {
        sp[reg] = acc[0][reg] * asv[0] + acc[1][reg] * asv[1]
                + acc[2][reg] * asv[2] + acc[3][reg] * asv[3];
        dp[reg] = acc[0][reg] * adv[0] + acc[1][reg] * adv[1]
                + acc[2][reg] * adv[2] + acc[3][reg] * adv[3];
    }
    #pragma unroll
    for (int m = 1; m <= 8; m <<= 1) {
        #pragma unroll
        for (int reg = 0; reg < 4; ++reg) {
            sp[reg] += __shfl_xor(sp[reg], m);
            dp[reg] += __shfl_xor(dp[reg], m);
        }
    }

    #pragma unroll
    for (int f = 0; f < 4; ++f) {
        uint2 st = { pkh2(acc[f][0], acc[f][1]), pkh2(acc[f][2], acc[f][3]) };
        *(uint2*)(h_t + (size_t)(hd * OUT_FEAT + 16 * f + r) * N_NODES + nb + 4 * q) = st;
    }

    if (r == 0) {
        #pragma unroll
        for (int reg = 0; reg < 4; ++reg) {
            int row = nb + 4 * q + reg;
            float s = sp[reg] * LOG2E;
            float d = dp[reg] * LOG2E;
            srcPK[hd * N_NODES + row] = pkh2(exp2f(s), exp2f(0.2f * s));
            dstE1[hd * N_NODES + row] = (f16)exp2f(d);
            dstE5[hd * N_NODES + row] = (f16)exp2f(0.2f * d);
        }
    }
}

// ---------------------------------------------------------------------------
// Phase 2 (r16/r17 body, unchanged): grid = 1024 blocks, 256 thr (4 waves).
// Decode: hd = bi>>7, rowgrp = (bi>>2)&31, chunk = bi&3. 64-m tiles,
// 16 iterations, all operands on the double-buffered global_load_lds
// pipeline; zero global loads in the K-loop.
// ---------------------------------------------------------------------------
__global__ __launch_bounds__(256, 4) void gat_phase2p(
    const f16* __restrict__ h_t,
    const unsigned* __restrict__ srcPK,
    const f16* __restrict__ dstE1,
    const f16* __restrict__ dstE5,
    const unsigned char* __restrict__ emask8,
    float* __restrict__ numA,
    float* __restrict__ denA)
{
    __shared__ f16 Vbuf[2][8320];   // 16640 B per buffer

    const int t    = threadIdx.x;
    const int lane = t & 63;
    const int wv   = t >> 6;
    const int r    = lane & 15;
    const int q    = lane >> 4;
    const int q8   = q * 8;

    const int hd     = blockIdx.x >> 7;
    const int rowgrp = (blockIdx.x >> 2) & 31;
    const int chunk  = blockIdx.x & 3;
    const int nblk   = rowgrp * 128;
    const int n0     = nblk + wv * 32;
    const int mbase  = chunk * 1024;

    HU s0u, s1u;
    s0u.u = srcPK[hd * N_NODES + n0 + r];
    s1u.u = srcPK[hd * N_NODES + n0 + 16 + r];
    const f16x2 se1_0 = { s0u.h[0], s0u.h[0] };
    const f16x2 se5_0 = { s0u.h[1], s0u.h[1] };
    const f16x2 se1_1 = { s1u.h[0], s1u.h[0] };
    const f16x2 se5_1 = { s1u.h[1], s1u.h[1] };

    const f16* Vhead = h_t + (size_t)hd * OUT_FEAT * N_NODES + mbase;
    const f16* srcV  = Vhead + (size_t)(t >> 2) * N_NODES + (t & 3) * 8;
    const unsigned char* srcM =
        emask8 + (size_t)(nblk + (t >> 1)) * N_NODES + mbase + (t & 1) * 16;
    const f16* ebase = ((t >> 2) & 1) ? dstE5 : dstE1;
    const f16* esrc  = ebase + (size_t)hd * N_NODES + mbase
                             + (t >> 3) * 32 + (t & 3) * 8;

    f32x4 acc0 = {}, acc1 = {}, acc2 = {}, acc3 = {}, accD0 = {};
    f32x4 acc4 = {}, acc5 = {}, acc6 = {}, acc7 = {}, accD1 = {};
    f16x8 ones;
    #pragma unroll
    for (int j = 0; j < 8; ++j) ones[j] = (f16)1.0f;

    auto stage = [&](int buf, int it) {
        const int c64 = it * 64;
        async_copy16(srcV + c64,      &Vbuf[buf][t * 8]);
        async_copy16(srcV + c64 + 32, &Vbuf[buf][2048 + t * 8]);
        async_copy16(srcM + c64,      &Vbuf[buf][4096 + t * 8]);
        async_copy16(srcM + c64 + 32, &Vbuf[buf][6144 + t * 8]);
        if (t < 16) async_copy16(esrc + c64, &Vbuf[buf][8192 + t * 8]);
    };

    stage(0, 0);

    for (int it = 0; it < 16; ++it) {
        const int cur = it & 1;
        __syncthreads();

        stage(1 - cur, (it + 1) & 15);

        #pragma unroll
        for (int s = 0; s < 2; ++s) {
            const int vb = s * 2048;
            uint4 e1v = *(const uint4*)(&Vbuf[cur][8192 + s * 64 + q8]);
            uint4 e5v = *(const uint4*)(&Vbuf[cur][8224 + s * 64 + q8]);
            uint2 m0v = *(const uint2*)(&Vbuf[cur][4096 + s * 2048 + (wv * 32 + r) * 16 + q * 4]);
            uint2 m1v = *(const uint2*)(&Vbuf[cur][4096 + s * 2048 + (wv * 32 + 16 + r) * 16 + q * 4]);

            unsigned e1d[4] = {e1v.x, e1v.y, e1v.z, e1v.w};
            unsigned e5d[4] = {e5v.x, e5v.y, e5v.z, e5v.w};
            unsigned mk0[4], mk1[4];
            mk0[0] = __builtin_amdgcn_perm(0u, m0v.x, 0x01010000u);
            mk0[1] = __builtin_amdgcn_perm(0u, m0v.x, 0x03030202u);
            mk0[2] = __builtin_amdgcn_perm(0u, m0v.y, 0x01010000u);
            mk0[3] = __builtin_amdgcn_perm(0u, m0v.y, 0x03030202u);
            mk1[0] = __builtin_amdgcn_perm(0u, m1v.x, 0x01010000u);
            mk1[1] = __builtin_amdgcn_perm(0u, m1v.x, 0x03030202u);
            mk1[2] = __builtin_amdgcn_perm(0u, m1v.y, 0x01010000u);
            mk1[3] = __builtin_amdgcn_perm(0u, m1v.y, 0x03030202u);

            A8 A0, A1;
            #pragma unroll
            for (int jp = 0; jp < 4; ++jp) {
                HU ed1; ed1.u = e1d[jp];
                HU ed5; ed5.u = e5d[jp];
                HU w0, w1;
                w0.h = __builtin_elementwise_max(se1_0 * ed1.h, se5_0 * ed5.h);
                w1.h = __builtin_elementwise_max(se1_1 * ed1.h, se5_1 * ed5.h);
                A0.u[jp] = w0.u & mk0[jp];
                A1.u[jp] = w1.u & mk1[jp];
            }

            f16x8 b0 = *(const f16x8*)(&Vbuf[cur][vb + (     r) * 32 + q8]);
            f16x8 b1 = *(const f16x8*)(&Vbuf[cur][vb + (16 + r) * 32 + q8]);
            f16x8 b2 = *(const f16x8*)(&Vbuf[cur][vb + (32 + r) * 32 + q8]);
            f16x8 b3 = *(const f16x8*)(&Vbuf[cur][vb + (48 + r) * 32 + q8]);

            acc0  = __builtin_amdgcn_mfma_f32_16x16x32_f16(A0.v, b0,   acc0,  0, 0, 0);
            acc1  = __builtin_amdgcn_mfma_f32_16x16x32_f16(A0.v, b1,   acc1,  0, 0, 0);
            acc2  = __builtin_amdgcn_mfma_f32_16x16x32_f16(A0.v, b2,   acc2,  0, 0, 0);
            acc3  = __builtin_amdgcn_mfma_f32_16x16x32_f16(A0.v, b3,   acc3,  0, 0, 0);
            accD0 = __builtin_amdgcn_mfma_f32_16x16x32_f16(A0.v, ones, accD0, 0, 0, 0);
            acc4  = __builtin_amdgcn_mfma_f32_16x16x32_f16(A1.v, b0,   acc4,  0, 0, 0);
            acc5  = __builtin_amdgcn_mfma_f32_16x16x32_f16(A1.v, b1,   acc5,  0, 0, 0);
            acc6  = __builtin_amdgcn_mfma_f32_16x16x32_f16(A1.v, b2,   acc6,  0, 0, 0);
            acc7  = __builtin_amdgcn_mfma_f32_16x16x32_f16(A1.v, b3,   acc7,  0, 0, 0);
            accD1 = __builtin_amdgcn_mfma_f32_16x16x32_f16(A1.v, ones, accD1, 0, 0, 0);
        }
    }

    #pragma unroll
    for (int reg = 0; reg < 4; ++reg) {
        int row0 = n0 + 4 * q + reg;
        int row1 = row0 + 16;
        atomicAdd(&numA[((size_t)row0 * NHEAD + hd) * 64 +  0 + r], acc0[reg]);
        atomicAdd(&numA[((size_t)row0 * NHEAD + hd) * 64 + 16 + r], acc1[reg]);
        atomicAdd(&numA[((size_t)row0 * NHEAD + hd) * 64 + 32 + r], acc2[reg]);
        atomicAdd(&numA[((size_t)row0 * NHEAD + hd) * 64 + 48 + r], acc3[reg]);
        atomicAdd(&numA[((size_t)row1 * NHEAD + hd) * 64 +  0 + r], acc4[reg]);
        atomicAdd(&numA[((size_t)row1 * NHEAD + hd) * 64 + 16 + r], acc5[reg]);
        atomicAdd(&numA[((size_t)row1 * NHEAD + hd) * 64 + 32 + r], acc6[reg]);
        atomicAdd(&numA[((size_t)row1 * NHEAD + hd) * 64 + 48 + r], acc7[reg]);
        if (r == 0) {
            atomicAdd(&denA[(size_t)row0 * NHEAD + hd], accD0[reg]);
            atomicAdd(&denA[(size_t)row1 * NHEAD + hd], accD1[reg]);
        }
    }
}

// ---------------------------------------------------------------------------
// Combine: divide, mean over heads, ELU. 256 blocks x 512 thr (2 cols/thr).
// ---------------------------------------------------------------------------
__global__ __launch_bounds__(512) void gat_combine(
    const float* __restrict__ numA,
    const float* __restrict__ denA,
    float* __restrict__ out)
{
    int gid = blockIdx.x * 512 + threadIdx.x;   // 0..131071
    int row = gid >> 5;
    int cp  = (gid & 31) * 2;
    float s0 = 0.f, s1 = 0.f;
    #pragma unroll
    for (int h = 0; h < NHEAD; ++h) {
        float2 v = *(const float2*)(numA + ((size_t)row * NHEAD + h) * 64 + cp);
        float inv = 1.f / denA[(size_t)row * NHEAD + h];
        s0 += v.x * inv;
        s1 += v.y * inv;
    }
    s0 *= 0.125f; s1 *= 0.125f;
    float e0 = s0 > 0.f ? s0 : expm1f(s0);
    float e1 = s1 > 0.f ? s1 : expm1f(s1);
    float2 pk = {e0, e1};
    *(float2*)(out + (size_t)row * OUT_FEAT + cp) = pk;
}

// ---------------------------------------------------------------------------
extern "C" void kernel_launch(void* const* d_in, const int* in_sizes, int n_in,
                              void* d_out, int out_size, void* d_ws, size_t ws_size,
                              hipStream_t stream)
{
    const float* x   = (const float*)d_in[0];
    const int*   adj = (const int*)d_in[1];
    const float* W   = (const float*)d_in[2];
    const float* a   = (const float*)d_in[3];
    float* out = (float*)d_out;

    char* ws = (char*)d_ws;
    f16*           h_t   = (f16*)ws;
    unsigned*      srcPK = (unsigned*)(ws + OFF_SRCPK);
    f16*           dstE1 = (f16*)(ws + OFF_DSTE1);
    f16*           dstE5 = (f16*)(ws + OFF_DSTE5);
    unsigned char* em    = (unsigned char*)(ws + OFF_EM);
    float*         numA  = (float*)(ws + OFF_NUMA);
    float*         denA  = (float*)(ws + OFF_DENA);

    gat_prep   <<<2576, 256, 0, stream>>>(adj, (unsigned*)em, numA,
                                          x, W, a, h_t, srcPK, dstE1, dstE5);
    gat_phase2p<<<1024, 256, 0, stream>>>(h_t, srcPK, dstE1, dstE5, em, numA, denA);
    gat_combine<<<256,  512, 0, stream>>>(numA, denA, out);
}

// Round 20
// 145.129 us; speedup vs baseline: 1.1891x; 1.1891x over previous
//
#include <hip/hip_runtime.h>
#include <hip/hip_fp16.h>
#include <cstdint>

#define N_NODES 4096
#define IN_FEAT 256
#define OUT_FEAT 64
#define NHEAD 8
#define LOG2E 1.4426950408889634f

typedef _Float16 f16;
typedef f16   f16x2 __attribute__((ext_vector_type(2)));
typedef f16   f16x8 __attribute__((ext_vector_type(8)));
typedef float f32x4 __attribute__((ext_vector_type(4)));

// ws layout (bytes) — total 38,797,312 == EXACTLY the r3-proven bound:
//   h_t   @ 0        : 8*64*4096*2 = 4194304   f16 [h][feat][node]
//   srcPK @ 4194304  : 8*4096*4    = 131072    dword {E1s,E5s} f16 pair per (h,n)
//   dstE1 @ 4325376  : 8*4096*2    = 65536     f16 exp2(t_d) per (h,m)
//   dstE5 @ 4390912  : 8*4096*2    = 65536     f16 exp2(0.2 t_d)
//   emask @ 4718592  : 4096*4096   = 16777216  byte 0xFF/0x00 = adj!=0
//   numP  @ 21495808 : 4*4096*8*64*2 = 16777216  f16 per-chunk partial nums
//   denP  @ 38273024 : 4*4096*8*4    = 524288    f32 per-chunk partial dens
// r20: exponentials pre-scaled by 2^-10 (split 2^-5 src / 2^-5 dst) so f16
// partials cannot overflow (r19's inf: unnormalized w up to ~2^15, partial
// sums > f16 max). num/den ratio is exactly invariant (power-of-2 scale on
// both). No atomics, no zeroing — every numP/denP element written once.
#define OFF_SRCPK 4194304
#define OFF_DSTE1 4325376
#define OFF_DSTE5 4390912
#define OFF_EM    4718592
#define OFF_NUMP  21495808ULL
#define OFF_DENP  38273024ULL

union HU { unsigned u; f16x2 h; };
union A8 { f16x8 v; unsigned u[4]; };

__device__ __forceinline__ void async_copy16(const void* g, void* l) {
    __builtin_amdgcn_global_load_lds(
        (const __attribute__((address_space(1))) void*)g,
        (__attribute__((address_space(3))) void*)l, 16, 0, 0);
}

static __device__ inline unsigned pkh2(float a, float b) {
    union { f16 h[2]; unsigned u; } t;
    t.h[0] = (f16)a; t.h[1] = (f16)b; return t.u;
}

// ---------------------------------------------------------------------------
// Fused front end:
//   [0,512)      phase1: h = x@W[h] (f16 MFMA), W read directly as f32
//   [512,1536)   adj -> emask bytes (elementwise, coalesced)
// ---------------------------------------------------------------------------
__global__ __launch_bounds__(256, 4) void gat_prep(
    const int*   __restrict__ adj,
    unsigned*    __restrict__ em32,
    const float* __restrict__ x,      // [4096][256]
    const float* __restrict__ W,      // [8][256][64]
    const float* __restrict__ a,      // [8][128]
    f16*      __restrict__ h_t,
    unsigned* __restrict__ srcPK,
    f16*      __restrict__ dstE1,
    f16*      __restrict__ dstE5)
{
    __shared__ f16 xs[16][264];

    if (blockIdx.x >= 512) {    // emask branch: wave per row
        const int bi   = blockIdx.x - 512;
        const int wv   = threadIdx.x >> 6;
        const int lane = threadIdx.x & 63;
        const int row  = bi * 4 + wv;
        const int* p   = adj + (size_t)row * N_NODES;
        unsigned* dst  = em32 + (size_t)row * (N_NODES / 4);
        #pragma unroll 4
        for (int s = 0; s < 16; ++s) {
            int4 v = *(const int4*)(p + s * 256 + lane * 4);
            unsigned d = (v.x ? 0x000000FFu : 0u) | (v.y ? 0x0000FF00u : 0u)
                       | (v.z ? 0x00FF0000u : 0u) | (v.w ? 0xFF000000u : 0u);
            dst[s * 64 + lane] = d;
        }
        return;
    }

    // ---- phase1 branch (blocks 0..511) ----
    const int lane = threadIdx.x & 63;
    const int wv   = threadIdx.x >> 6;
    const int tile = blockIdx.x >> 1;
    const int hd   = (blockIdx.x & 1) * 4 + wv;
    const int r    = lane & 15;
    const int q    = lane >> 4;
    const int nb   = tile * 16;

    #pragma unroll
    for (int c = 0; c < 4; ++c) {
        int idx = c * 1024 + threadIdx.x * 4;
        int row = idx >> 8, col = idx & 255;
        float4 v = *(const float4*)(x + (size_t)(nb + row) * IN_FEAT + col);
        uint2 st = { pkh2(v.x, v.y), pkh2(v.z, v.w) };
        *(uint2*)(&xs[row][col]) = st;
    }
    __syncthreads();

    const float* Wg = W + (size_t)hd * (IN_FEAT * OUT_FEAT);
    f32x4 acc[4] = {};

    #pragma unroll 2
    for (int k0 = 0; k0 < IN_FEAT; k0 += 32) {
        f16x8 af = *(const f16x8*)(&xs[r][k0 + q * 8]);
        #pragma unroll
        for (int f = 0; f < 4; ++f) {
            f16x8 bf;
            #pragma unroll
            for (int j = 0; j < 8; ++j)
                bf[j] = (f16)Wg[(size_t)(k0 + q * 8 + j) * OUT_FEAT + 16 * f + r];
            acc[f] = __builtin_amdgcn_mfma_f32_16x16x32_f16(af, bf, acc[f], 0, 0, 0);
        }
    }

    float asv[4], adv[4];
    #pragma unroll
    for (int f = 0; f < 4; ++f) {
        asv[f] = a[hd * 128 + 16 * f + r];
        adv[f] = a[hd * 128 + 64 + 16 * f + r];
    }
    float sp[4], dp[4];
    #pragma unroll
    for (int reg = 0; reg < 4; ++reg) {
        sp[reg] = acc[0][reg] * asv[0] + acc[1][reg] * asv[1]
                + acc[2][reg] * asv[2] + acc[3][reg] * asv[3];
        dp[reg] = acc[0][reg] * adv[0] + acc[1][reg] * adv[1]
                + acc[2][reg] * adv[2] + acc[3][reg] * adv[3];
    }
    #pragma unroll
    for (int m = 1; m <= 8; m <<= 1) {
        #pragma unroll
        for (int reg = 0; reg < 4; ++reg) {
            sp[reg] += __shfl_xor(sp[reg], m);
            dp[reg] += __shfl_xor(dp[reg], m);
        }
    }

    #pragma unroll
    for (int f = 0; f < 4; ++f) {
        uint2 st = { pkh2(acc[f][0], acc[f][1]), pkh2(acc[f][2], acc[f][3]) };
        *(uint2*)(h_t + (size_t)(hd * OUT_FEAT + 16 * f + r) * N_NODES + nb + 4 * q) = st;
    }

    if (r == 0) {
        #pragma unroll
        for (int reg = 0; reg < 4; ++reg) {
            int row = nb + 4 * q + reg;
            float s = sp[reg] * LOG2E;
            float d = dp[reg] * LOG2E;
            // 2^-5 bias each side => w scaled by exactly 2^-10 (overflow-proof
            // f16 partials; num/den ratio invariant — both carry the factor)
            srcPK[hd * N_NODES + row] = pkh2(exp2f(s - 5.0f), exp2f(0.2f * s - 5.0f));
            dstE1[hd * N_NODES + row] = (f16)exp2f(d - 5.0f);
            dstE5[hd * N_NODES + row] = (f16)exp2f(0.2f * d - 5.0f);
        }
    }
}

// ---------------------------------------------------------------------------
// Phase 2 (r16 K-loop): grid = 1024 blocks, 256 thr (4 waves, wave = 32 rows).
// Decode: hd = bi>>7, rowgrp = (bi>>2)&31, chunk = bi&3. 64-m tiles,
// 16 iterations, all operands on the double-buffered global_load_lds
// pipeline; zero global loads in the K-loop.
// Epilogue: non-atomic per-chunk partial stores (f16 num, f32 den).
// ---------------------------------------------------------------------------
__global__ __launch_bounds__(256, 4) void gat_phase2p(
    const f16* __restrict__ h_t,
    const unsigned* __restrict__ srcPK,
    const f16* __restrict__ dstE1,
    const f16* __restrict__ dstE5,
    const unsigned char* __restrict__ emask8,
    f16*   __restrict__ numP,
    float* __restrict__ denP)
{
    __shared__ f16 Vbuf[2][8320];   // 16640 B per buffer

    const int t    = threadIdx.x;
    const int lane = t & 63;
    const int wv   = t >> 6;
    const int r    = lane & 15;
    const int q    = lane >> 4;
    const int q8   = q * 8;

    const int hd     = blockIdx.x >> 7;
    const int rowgrp = (blockIdx.x >> 2) & 31;
    const int chunk  = blockIdx.x & 3;
    const int nblk   = rowgrp * 128;
    const int n0     = nblk + wv * 32;
    const int mbase  = chunk * 1024;

    HU s0u, s1u;
    s0u.u = srcPK[hd * N_NODES + n0 + r];
    s1u.u = srcPK[hd * N_NODES + n0 + 16 + r];
    const f16x2 se1_0 = { s0u.h[0], s0u.h[0] };
    const f16x2 se5_0 = { s0u.h[1], s0u.h[1] };
    const f16x2 se1_1 = { s1u.h[0], s1u.h[0] };
    const f16x2 se5_1 = { s1u.h[1], s1u.h[1] };

    const f16* Vhead = h_t + (size_t)hd * OUT_FEAT * N_NODES + mbase;
    const f16* srcV  = Vhead + (size_t)(t >> 2) * N_NODES + (t & 3) * 8;
    const unsigned char* srcM =
        emask8 + (size_t)(nblk + (t >> 1)) * N_NODES + mbase + (t & 1) * 16;
    const f16* ebase = ((t >> 2) & 1) ? dstE5 : dstE1;
    const f16* esrc  = ebase + (size_t)hd * N_NODES + mbase
                             + (t >> 3) * 32 + (t & 3) * 8;

    f32x4 acc0 = {}, acc1 = {}, acc2 = {}, acc3 = {}, accD0 = {};
    f32x4 acc4 = {}, acc5 = {}, acc6 = {}, acc7 = {}, accD1 = {};
    f16x8 ones;
    #pragma unroll
    for (int j = 0; j < 8; ++j) ones[j] = (f16)1.0f;

    auto stage = [&](int buf, int it) {
        const int c64 = it * 64;
        async_copy16(srcV + c64,      &Vbuf[buf][t * 8]);
        async_copy16(srcV + c64 + 32, &Vbuf[buf][2048 + t * 8]);
        async_copy16(srcM + c64,      &Vbuf[buf][4096 + t * 8]);
        async_copy16(srcM + c64 + 32, &Vbuf[buf][6144 + t * 8]);
        if (t < 16) async_copy16(esrc + c64, &Vbuf[buf][8192 + t * 8]);
    };

    stage(0, 0);

    for (int it = 0; it < 16; ++it) {
        const int cur = it & 1;
        __syncthreads();

        stage(1 - cur, (it + 1) & 15);

        #pragma unroll
        for (int s = 0; s < 2; ++s) {
            const int vb = s * 2048;
            uint4 e1v = *(const uint4*)(&Vbuf[cur][8192 + s * 64 + q8]);
            uint4 e5v = *(const uint4*)(&Vbuf[cur][8224 + s * 64 + q8]);
            uint2 m0v = *(const uint2*)(&Vbuf[cur][4096 + s * 2048 + (wv * 32 + r) * 16 + q * 4]);
            uint2 m1v = *(const uint2*)(&Vbuf[cur][4096 + s * 2048 + (wv * 32 + 16 + r) * 16 + q * 4]);

            unsigned e1d[4] = {e1v.x, e1v.y, e1v.z, e1v.w};
            unsigned e5d[4] = {e5v.x, e5v.y, e5v.z, e5v.w};
            unsigned mk0[4], mk1[4];
            mk0[0] = __builtin_amdgcn_perm(0u, m0v.x, 0x01010000u);
            mk0[1] = __builtin_amdgcn_perm(0u, m0v.x, 0x03030202u);
            mk0[2] = __builtin_amdgcn_perm(0u, m0v.y, 0x01010000u);
            mk0[3] = __builtin_amdgcn_perm(0u, m0v.y, 0x03030202u);
            mk1[0] = __builtin_amdgcn_perm(0u, m1v.x, 0x01010000u);
            mk1[1] = __builtin_amdgcn_perm(0u, m1v.x, 0x03030202u);
            mk1[2] = __builtin_amdgcn_perm(0u, m1v.y, 0x01010000u);
            mk1[3] = __builtin_amdgcn_perm(0u, m1v.y, 0x03030202u);

            A8 A0, A1;
            #pragma unroll
            for (int jp = 0; jp < 4; ++jp) {
                HU ed1; ed1.u = e1d[jp];
                HU ed5; ed5.u = e5d[jp];
                HU w0, w1;
                w0.h = __builtin_elementwise_max(se1_0 * ed1.h, se5_0 * ed5.h);
                w1.h = __builtin_elementwise_max(se1_1 * ed1.h, se5_1 * ed5.h);
                A0.u[jp] = w0.u & mk0[jp];
                A1.u[jp] = w1.u & mk1[jp];
            }

            f16x8 b0 = *(const f16x8*)(&Vbuf[cur][vb + (     r) * 32 + q8]);
            f16x8 b1 = *(const f16x8*)(&Vbuf[cur][vb + (16 + r) * 32 + q8]);
            f16x8 b2 = *(const f16x8*)(&Vbuf[cur][vb + (32 + r) * 32 + q8]);
            f16x8 b3 = *(const f16x8*)(&Vbuf[cur][vb + (48 + r) * 32 + q8]);

            acc0  = __builtin_amdgcn_mfma_f32_16x16x32_f16(A0.v, b0,   acc0,  0, 0, 0);
            acc1  = __builtin_amdgcn_mfma_f32_16x16x32_f16(A0.v, b1,   acc1,  0, 0, 0);
            acc2  = __builtin_amdgcn_mfma_f32_16x16x32_f16(A0.v, b2,   acc2,  0, 0, 0);
            acc3  = __builtin_amdgcn_mfma_f32_16x16x32_f16(A0.v, b3,   acc3,  0, 0, 0);
            accD0 = __builtin_amdgcn_mfma_f32_16x16x32_f16(A0.v, ones, accD0, 0, 0, 0);
            acc4  = __builtin_amdgcn_mfma_f32_16x16x32_f16(A1.v, b0,   acc4,  0, 0, 0);
            acc5  = __builtin_amdgcn_mfma_f32_16x16x32_f16(A1.v, b1,   acc5,  0, 0, 0);
            acc6  = __builtin_amdgcn_mfma_f32_16x16x32_f16(A1.v, b2,   acc6,  0, 0, 0);
            acc7  = __builtin_amdgcn_mfma_f32_16x16x32_f16(A1.v, b3,   acc7,  0, 0, 0);
            accD1 = __builtin_amdgcn_mfma_f32_16x16x32_f16(A1.v, ones, accD1, 0, 0, 0);
        }
    }

    // non-atomic per-chunk partial stores (each element written exactly once)
    const size_t cb = (size_t)chunk * N_NODES;
    #pragma unroll
    for (int reg = 0; reg < 4; ++reg) {
        int row0 = n0 + 4 * q + reg;
        int row1 = row0 + 16;
        size_t b0 = ((cb + row0) * NHEAD + hd) * 64;
        size_t b1 = ((cb + row1) * NHEAD + hd) * 64;
        numP[b0 +      r] = (f16)acc0[reg];
        numP[b0 + 16 + r] = (f16)acc1[reg];
        numP[b0 + 32 + r] = (f16)acc2[reg];
        numP[b0 + 48 + r] = (f16)acc3[reg];
        numP[b1 +      r] = (f16)acc4[reg];
        numP[b1 + 16 + r] = (f16)acc5[reg];
        numP[b1 + 32 + r] = (f16)acc6[reg];
        numP[b1 + 48 + r] = (f16)acc7[reg];
        if (r == 0) {
            denP[(cb + row0) * NHEAD + hd] = accD0[reg];
            denP[(cb + row1) * NHEAD + hd] = accD1[reg];
        }
    }
}

// ---------------------------------------------------------------------------
// Combine: sum 4 chunk partials, divide, mean over heads, ELU.
// 256 blocks x 512 thr (2 cols/thr).
// ---------------------------------------------------------------------------
__global__ __launch_bounds__(512) void gat_combine(
    const f16*   __restrict__ numP,
    const float* __restrict__ denP,
    float* __restrict__ out)
{
    int gid = blockIdx.x * 512 + threadIdx.x;   // 0..131071
    int row = gid >> 5;
    int cp  = (gid & 31) * 2;
    float s0 = 0.f, s1 = 0.f;
    #pragma unroll
    for (int h = 0; h < NHEAD; ++h) {
        float n0 = 0.f, n1 = 0.f, den = 0.f;
        #pragma unroll
        for (int c = 0; c < 4; ++c) {
            size_t base = ((size_t)c * N_NODES + row) * NHEAD + h;
            HU u; u.u = *(const unsigned*)(numP + base * 64 + cp);
            n0 += (float)u.h[0];
            n1 += (float)u.h[1];
            den += denP[base];
        }
        float inv = 1.f / den;
        s0 += n0 * inv;
        s1 += n1 * inv;
    }
    s0 *= 0.125f; s1 *= 0.125f;
    float e0 = s0 > 0.f ? s0 : expm1f(s0);
    float e1 = s1 > 0.f ? s1 : expm1f(s1);
    float2 pk = {e0, e1};
    *(float2*)(out + (size_t)row * OUT_FEAT + cp) = pk;
}

// ---------------------------------------------------------------------------
extern "C" void kernel_launch(void* const* d_in, const int* in_sizes, int n_in,
                              void* d_out, int out_size, void* d_ws, size_t ws_size,
                              hipStream_t stream)
{
    const float* x   = (const float*)d_in[0];
    const int*   adj = (const int*)d_in[1];
    const float* W   = (const float*)d_in[2];
    const float* a   = (const float*)d_in[3];
    float* out = (float*)d_out;

    char* ws = (char*)d_ws;
    f16*           h_t   = (f16*)ws;
    unsigned*      srcPK = (unsigned*)(ws + OFF_SRCPK);
    f16*           dstE1 = (f16*)(ws + OFF_DSTE1);
    f16*           dstE5 = (f16*)(ws + OFF_DSTE5);
    unsigned char* em    = (unsigned char*)(ws + OFF_EM);
    f16*           numP  = (f16*)(ws + OFF_NUMP);
    float*         denP  = (float*)(ws + OFF_DENP);

    gat_prep   <<<1536, 256, 0, stream>>>(adj, (unsigned*)em,
                                          x, W, a, h_t, srcPK, dstE1, dstE5);
    gat_phase2p<<<1024, 256, 0, stream>>>(h_t, srcPK, dstE1, dstE5, em, numP, denP);
    gat_combine<<<256,  512, 0, stream>>>(numP, denP, out);
}